// Round 1
// baseline (237.123 us; speedup 1.0000x reference)
//
#include <hip/hip_runtime.h>
#include <hip/hip_bf16.h>
#include <stdint.h>

// B=256 batches, T=256 seq, D=512 embed, HD=64 head dim
#define NB 256
#define NT 256
#define ND 512
#define NH 64

typedef __bf16 bf16;
typedef __bf16 bf16x4 __attribute__((ext_vector_type(4)));
typedef __bf16 bf16x8 __attribute__((ext_vector_type(8)));
typedef float f32x4 __attribute__((ext_vector_type(4)));

static __device__ __forceinline__ f32x4 mfma16(bf16x8 a, bf16x8 b, f32x4 c) {
    return __builtin_amdgcn_mfma_f32_16x16x32_bf16(a, b, c, 0, 0, 0);
}

static __device__ __forceinline__ bf16x8 cvt8(f32x4 a, f32x4 b) {
    bf16x8 r;
    r[0] = (bf16)a.x; r[1] = (bf16)a.y; r[2] = (bf16)a.z; r[3] = (bf16)a.w;
    r[4] = (bf16)b.x; r[5] = (bf16)b.y; r[6] = (bf16)b.z; r[7] = (bf16)b.w;
    return r;
}

// ---------------- Kernel 0: W fp32 -> bf16, packed [192][512] (q rows 0-63, k 64-127, v 128-191)
__global__ __launch_bounds__(256) void wconv_kernel(
        const float* __restrict__ Wq, const float* __restrict__ Wk,
        const float* __restrict__ Wv, bf16* __restrict__ wbf) {
    int idx = (blockIdx.x * 256 + threadIdx.x) * 4;  // 0..98300
    const float* src;
    if (idx < 64 * ND)       src = Wq + idx;
    else if (idx < 128 * ND) src = Wk + (idx - 64 * ND);
    else                     src = Wv + (idx - 128 * ND);
    f32x4 v = *reinterpret_cast<const f32x4*>(src);
    bf16x4 o;
    o[0] = (bf16)v.x; o[1] = (bf16)v.y; o[2] = (bf16)v.z; o[3] = (bf16)v.w;
    *reinterpret_cast<bf16x4*>(wbf + idx) = o;
}

// ---------------- Kernel 1: fused q/k/v projection GEMM
// grid.x = 1024 (64 rows each), 256 threads (4 waves), wave w owns cols 48w..48w+47 of [q|k|v]
// LDS: xt [64][64] bf16 @0 (8KB, swizzled), wt [192][64] bf16 @8192 (24KB, swizzled)
__global__ __launch_bounds__(256) void qkv_gemm_kernel(
        const float* __restrict__ x, const bf16* __restrict__ wbf,
        bf16* __restrict__ qws, bf16* __restrict__ kws, bf16* __restrict__ vws) {
    __shared__ alignas(16) char lds[32768];
    const int t = threadIdx.x;
    const int lane = t & 63, wave = t >> 6;
    const long m0 = (long)blockIdx.x * 64;

    f32x4 acc[4][3] = {};

    for (int kk = 0; kk < ND; kk += 64) {
        // stage x tile: 64 rows x 64 k fp32 -> bf16
        {
            int row = t >> 2, kc = (t & 3) * 16;
            const float* src = x + (m0 + row) * ND + kk + kc;
            f32x4 a = *reinterpret_cast<const f32x4*>(src);
            f32x4 b = *reinterpret_cast<const f32x4*>(src + 4);
            f32x4 c = *reinterpret_cast<const f32x4*>(src + 8);
            f32x4 d = *reinterpret_cast<const f32x4*>(src + 12);
            int base = row * 128 + kc * 2;
            int sw = (row & 7) << 4;
            *reinterpret_cast<bf16x8*>(lds + ((base) ^ sw)) = cvt8(a, b);
            *reinterpret_cast<bf16x8*>(lds + ((base + 16) ^ sw)) = cvt8(c, d);
        }
        // stage W^T slice: [192 n][64 k] bf16 (already bf16 in wbf)
        #pragma unroll
        for (int s = 0; s < 3; ++s) {
            int f = t + 256 * s;              // 0..767
            int n = f >> 2, kc = (f & 3) * 16;
            const bf16* src = wbf + n * ND + kk + kc;
            bf16x8 lo = *reinterpret_cast<const bf16x8*>(src);
            bf16x8 hi = *reinterpret_cast<const bf16x8*>(src + 8);
            int base = n * 128 + kc * 2;
            int sw = (n & 7) << 4;
            *reinterpret_cast<bf16x8*>(lds + 8192 + ((base) ^ sw)) = lo;
            *reinterpret_cast<bf16x8*>(lds + 8192 + ((base + 16) ^ sw)) = hi;
        }
        __syncthreads();

        #pragma unroll
        for (int k2 = 0; k2 < 2; ++k2) {
            const int koff = (k2 * 32 + (lane >> 4) * 8) * 2;
            bf16x8 Af[4];
            #pragma unroll
            for (int ri = 0; ri < 4; ++ri) {
                int row = ri * 16 + (lane & 15);
                Af[ri] = *reinterpret_cast<const bf16x8*>(
                    lds + ((row * 128 + koff) ^ ((row & 7) << 4)));
            }
            #pragma unroll
            for (int ci = 0; ci < 3; ++ci) {
                int n = wave * 48 + ci * 16 + (lane & 15);
                bf16x8 Bf = *reinterpret_cast<const bf16x8*>(
                    lds + 8192 + ((n * 128 + koff) ^ ((n & 7) << 4)));
                #pragma unroll
                for (int ri = 0; ri < 4; ++ri)
                    acc[ri][ci] = mfma16(Af[ri], Bf, acc[ri][ci]);
            }
        }
        __syncthreads();
    }

    // epilogue: scatter bf16 stores; q gets the HD^-0.5 = 0.125 scale folded in
    #pragma unroll
    for (int ci = 0; ci < 3; ++ci) {
        int n = wave * 48 + ci * 16 + (lane & 15);
        int sel = n >> 6, hd = n & 63;
        bf16* dst = sel == 0 ? qws : (sel == 1 ? kws : vws);
        float scale = sel == 0 ? 0.125f : 1.0f;
        #pragma unroll
        for (int ri = 0; ri < 4; ++ri) {
            #pragma unroll
            for (int r = 0; r < 4; ++r) {
                long row = m0 + ri * 16 + (lane >> 4) * 4 + r;
                dst[row * NH + hd] = (bf16)(acc[ri][ci][r] * scale);
            }
        }
    }
}

// ---------------- Kernel 2: causal attention, one WG per (q-block of 64 rows, batch)
// LDS 64KB: K [256][64] bf16 @0 (32KB, row-swizzled; reused as per-wave P [16][256] after S)
//           Vt [64 hd][256 t] bf16 @32768 (32KB, row-swizzled)
__global__ __launch_bounds__(256) void attn_kernel(
        const bf16* __restrict__ qws, const bf16* __restrict__ kws,
        const bf16* __restrict__ vws, float* __restrict__ out) {
    __shared__ alignas(16) char lds[65536];
    const int t = threadIdx.x, lane = t & 63, wave = t >> 6;
    const int qb = blockIdx.x, b = blockIdx.y;
    const int KV = (qb + 1) * 64;          // valid kv length for this q-block
    const long bbase = (long)b * NT;

    // ---- stage K (row-major, swizzled) and V^T (scatter, swizzled)
    {
        int rr = t >> 2, c0 = (t & 3) * 16;
        for (int s = 0; s < KV; s += 64) {
            int row = rr + s;
            const bf16* ksrc = kws + (bbase + row) * NH + c0;
            bf16x8 klo = *reinterpret_cast<const bf16x8*>(ksrc);
            bf16x8 khi = *reinterpret_cast<const bf16x8*>(ksrc + 8);
            int base = row * 128 + c0 * 2;
            int sw = (row & 7) << 4;
            *reinterpret_cast<bf16x8*>(lds + ((base) ^ sw)) = klo;
            *reinterpret_cast<bf16x8*>(lds + ((base + 16) ^ sw)) = khi;

            const bf16* vsrc = vws + (bbase + row) * NH + c0;
            bf16x8 vlo = *reinterpret_cast<const bf16x8*>(vsrc);
            bf16x8 vhi = *reinterpret_cast<const bf16x8*>(vsrc + 8);
            #pragma unroll
            for (int j = 0; j < 8; ++j) {
                int c = c0 + j;
                *reinterpret_cast<bf16*>(lds + 32768 + ((c * 512 + row * 2) ^ ((c & 7) << 4))) = vlo[j];
                int c2 = c0 + 8 + j;
                *reinterpret_cast<bf16*>(lds + 32768 + ((c2 * 512 + row * 2) ^ ((c2 & 7) << 4))) = vhi[j];
            }
        }
    }
    // ---- Q fragments direct from global (q already scaled by 0.125)
    bf16x8 Qf[2];
    {
        long qrow = bbase + qb * 64 + wave * 16 + (lane & 15);
        const bf16* qsrc = qws + qrow * NH + (lane >> 4) * 8;
        Qf[0] = *reinterpret_cast<const bf16x8*>(qsrc);
        Qf[1] = *reinterpret_cast<const bf16x8*>(qsrc + 32);
    }
    __syncthreads();

    // wave w owns q rows [qb*64 + 16w, +16); it needs col tiles 0..ncolt-1
    const int ncolt = qb * 4 + wave + 1;
    const int ncolt2 = (ncolt + 1) & ~1;   // round up to even (extra tile fully masked -> P=0)

    f32x4 S[16] = {};
    #pragma unroll
    for (int c = 0; c < 16; ++c) {
        if (c < ncolt2) {
            #pragma unroll
            for (int k2 = 0; k2 < 2; ++k2) {
                int col = c * 16 + (lane & 15);
                int koff = (k2 * 32 + (lane >> 4) * 8) * 2;
                bf16x8 Bf = *reinterpret_cast<const bf16x8*>(
                    lds + ((col * 128 + koff) ^ ((col & 7) << 4)));
                S[c] = mfma16(Qf[k2], Bf, S[c]);
            }
        }
    }

    // ---- causal mask + row softmax (row i=(lane>>4)*4+r spread over 16 lanes of the group)
    const int qrow0 = qb * 64 + wave * 16 + (lane >> 4) * 4;
    float m[4], sum[4];
    #pragma unroll
    for (int r = 0; r < 4; ++r) { m[r] = -1e30f; sum[r] = 0.0f; }
    #pragma unroll
    for (int c = 0; c < 16; ++c) {
        if (c < ncolt2) {
            int col = c * 16 + (lane & 15);
            #pragma unroll
            for (int r = 0; r < 4; ++r) {
                float v = (col <= qrow0 + r) ? S[c][r] : -1e30f;
                S[c][r] = v;
                m[r] = fmaxf(m[r], v);
            }
        }
    }
    #pragma unroll
    for (int r = 0; r < 4; ++r) {
        m[r] = fmaxf(m[r], __shfl_xor(m[r], 1));
        m[r] = fmaxf(m[r], __shfl_xor(m[r], 2));
        m[r] = fmaxf(m[r], __shfl_xor(m[r], 4));
        m[r] = fmaxf(m[r], __shfl_xor(m[r], 8));
    }
    #pragma unroll
    for (int c = 0; c < 16; ++c) {
        if (c < ncolt2) {
            #pragma unroll
            for (int r = 0; r < 4; ++r) {
                float p = __expf(S[c][r] - m[r]);
                S[c][r] = p;
                sum[r] += p;
            }
        }
    }
    #pragma unroll
    for (int r = 0; r < 4; ++r) {
        sum[r] += __shfl_xor(sum[r], 1);
        sum[r] += __shfl_xor(sum[r], 2);
        sum[r] += __shfl_xor(sum[r], 4);
        sum[r] += __shfl_xor(sum[r], 8);
    }

    __syncthreads();   // everyone done reading K -> safe to overwrite with P

    // ---- write P (unnormalized, <=1.0) as bf16 to own region [16][256] @ wave*8192
    char* plds = lds + wave * 8192;
    #pragma unroll
    for (int c = 0; c < 16; ++c) {
        if (c < ncolt2) {
            int colp = c * 16 + (lane & 15);
            #pragma unroll
            for (int r = 0; r < 4; ++r) {
                int rowp = (lane >> 4) * 4 + r;
                *reinterpret_cast<bf16*>(plds + ((rowp * 512 + colp * 2) ^ ((rowp & 7) << 4))) =
                    (bf16)S[c][r];
            }
        }
    }
    __syncthreads();

    // ---- O = P @ V  (A = P [16 x KV], B = Vt)
    f32x4 O[4] = {};
    #pragma unroll
    for (int kk2 = 0; kk2 < 8; ++kk2) {
        if (kk2 < (ncolt2 >> 1)) {
            int koff = (kk2 * 32 + (lane >> 4) * 8) * 2;
            int rowp = lane & 15;
            bf16x8 Pf = *reinterpret_cast<const bf16x8*>(
                plds + ((rowp * 512 + koff) ^ ((rowp & 7) << 4)));
            #pragma unroll
            for (int cb = 0; cb < 4; ++cb) {
                int hd = cb * 16 + (lane & 15);
                bf16x8 Vf = *reinterpret_cast<const bf16x8*>(
                    lds + 32768 + ((hd * 512 + koff) ^ ((hd & 7) << 4)));
                O[cb] = mfma16(Pf, Vf, O[cb]);
            }
        }
    }

    float rinv[4];
    #pragma unroll
    for (int r = 0; r < 4; ++r) rinv[r] = 1.0f / sum[r];

    #pragma unroll
    for (int cb = 0; cb < 4; ++cb) {
        int hd = cb * 16 + (lane & 15);
        #pragma unroll
        for (int r = 0; r < 4; ++r) {
            long orow = bbase + qb * 64 + wave * 16 + (lane >> 4) * 4 + r;
            out[orow * NH + hd] = O[cb][r] * rinv[r];
        }
    }
}

// ---------------- launch
extern "C" void kernel_launch(void* const* d_in, const int* in_sizes, int n_in,
                              void* d_out, int out_size, void* d_ws, size_t ws_size,
                              hipStream_t stream) {
    const float* x  = (const float*)d_in[0];
    const float* Wq = (const float*)d_in[1];
    const float* Wk = (const float*)d_in[2];
    const float* Wv = (const float*)d_in[3];
    float* out = (float*)d_out;

    // ws layout: wbf [192][512] bf16 (192KB), then q/k/v [B*T][64] bf16 (8MB each). ~24.4MB total.
    char* ws = (char*)d_ws;
    bf16* wbf = (bf16*)ws;
    bf16* qws = (bf16*)(ws + 0x30000);
    bf16* kws = (bf16*)(ws + 0x30000 + 8388608);
    bf16* vws = (bf16*)(ws + 0x30000 + 2 * 8388608);

    wconv_kernel<<<96, 256, 0, stream>>>(Wq, Wk, Wv, wbf);
    qkv_gemm_kernel<<<1024, 256, 0, stream>>>(x, wbf, qws, kws, vws);
    attn_kernel<<<dim3(4, NB), 256, 0, stream>>>(qws, kws, vws, out);
}